// Round 5
// baseline (114.232 us; speedup 1.0000x reference)
//
#include <hip/hip_runtime.h>
#include <hip/hip_bf16.h>

#define Dd   64
#define BWk  31
#define PX   16
#define NTH  256
#define NS   40                 // wYb k-stride in bf16 units (multiple of 8 -> 16B aligned frags)
#define JS   (32 * NS)          // per-j stride

typedef float  f32x4   __attribute__((ext_vector_type(4)));
typedef short  bf16x8  __attribute__((ext_vector_type(8)));
typedef float  float4a __attribute__((ext_vector_type(4), aligned(4)));

__device__ __forceinline__ unsigned pk2(float lo, float hi) {
    __hip_bfloat162 h = __float22bfloat162_rn(make_float2(lo, hi));
    union { __hip_bfloat162 h; unsigned u; } c; c.h = h; return c.u;
}

__global__ __launch_bounds__(NTH, 3)
void band_mfma(const float* __restrict__ pw,
               const float* __restrict__ x,
               float* __restrict__ out)
{
    // y-interpolated coarse weights, bf16: [j=6][n=32][k=32 (pad k31=0), stride 40]
    __shared__ unsigned short wYb[6 * JS];

    const int tid = threadIdx.x;

    // --- XCD-aware swizzle: consecutive logical tiles share an XCD's L2 ---
    // hw bid round-robins over 8 XCDs; logical = xcd*512 + slot gives each XCD
    // a contiguous run of 512 tiles = 32 full y-rows (all bx adjacent).
    const unsigned bid = blockIdx.x;                 // 0..4095
    const unsigned logical = (bid & 7u) * 512u + (bid >> 3);
    const int bx = logical & 15;
    const int y  = logical >> 4;
    const int x0 = bx * PX;

    // exact scale-4 half-pixel y interpolation (validated rounds 1-4)
    const int yq = y >> 2, ry = y & 3;
    const int y0i = yq + ((ry < 2) ? -1 : 0);
    const float fy = 0.125f + 0.25f * (float)((ry + 2) & 3);
    const int y0c = (y0i < 0) ? 0 : y0i;
    const int y1c = (y0i + 1 > Dd - 1) ? Dd - 1 : (y0i + 1);
    const int cxbase = (x0 >> 2) - 1;

    // ---- stage wYb: task = (n = tid>>3, k0 = (tid&7)*4) x (j 0..5) ----
    {
        const int k0 = (tid & 7) << 2;          // 0,4,...,28
        const int n  = tid >> 3;                // 0..31
        const bool lastk = (k0 == 28);
        #pragma unroll
        for (int j = 0; j < 6; ++j) {
            int cx = cxbase + j;
            cx = (cx < 0) ? 0 : ((cx > Dd - 1) ? Dd - 1 : cx);
            const size_t rb = ((size_t)n * 4096 + (size_t)cx) * BWk + k0;
            float4a a = *(const float4a*)(pw + rb + (size_t)y0c * (Dd * BWk));
            float4a b = *(const float4a*)(pw + rb + (size_t)y1c * (Dd * BWk));
            float v0 = fmaf(fy, b.x - a.x, a.x);
            float v1 = fmaf(fy, b.y - a.y, a.y);
            float v2 = fmaf(fy, b.z - a.z, a.z);
            float v3 = lastk ? 0.f : fmaf(fy, b.w - a.w, a.w);   // k=31 pad = 0
            *(uint2*)&wYb[j * JS + n * NS + k0] = make_uint2(pk2(v0, v1), pk2(v2, v3));
        }
    }
    __syncthreads();

    const int lane = tid & 63;
    const int px   = lane & 15;      // MFMA column = pixel
    const int q    = lane >> 4;      // k-slice / C row group

    // A-frags: A[j][mh] = wY_j[n = mh*16 + px][k = 8q..8q+7]  (register-cached)
    bf16x8 A[6][2];
    #pragma unroll
    for (int j = 0; j < 6; ++j) {
        A[j][0] = *(const bf16x8*)&wYb[j * JS + px * NS + q * 8];
        A[j][1] = *(const bf16x8*)&wYb[j * JS + (16 + px) * NS + q * 8];
    }

    // per-pixel x-interp coefficients c_j (2 of 6 nonzero)
    const int rx = px & 3;
    const float fx = 0.125f + 0.25f * (float)((rx + 2) & 3);
    const int j0 = (px >> 2) + ((rx < 2) ? 0 : 1);   // 0..4
    float c[6];
    #pragma unroll
    for (int j = 0; j < 6; ++j)
        c[j] = (j == j0) ? (1.f - fx) : ((j == j0 + 1) ? fx : 0.f);

    const int bc0 = (tid >> 6) * 8;                 // 8 bc per wave
    const int gxb = x0 + px + q * 8 - 15;           // B element i -> x[gxb + i]
    const bool edgeblk = (bx == 0) || (bx == 15);
    const size_t yoff = (size_t)y * 256 + (size_t)(x0 + px);
    const f32x4 zero = {0.f, 0.f, 0.f, 0.f};

    // --- x row loads: prefetch one bc ahead to overlap with MFMA/blend ---
    float4a nv0, nv1;
    {
        const float* xrow = x + ((size_t)bc0 * 256 + y) * 256;
        if (!edgeblk) {
            nv0 = *(const float4a*)(xrow + gxb);
            nv1 = *(const float4a*)(xrow + gxb + 4);
        } else {
            float t[8];
            #pragma unroll
            for (int i = 0; i < 8; ++i) {
                int gx = gxb + i;
                t[i] = ((unsigned)gx < 256u) ? xrow[gx] : 0.f;
            }
            nv0 = *(float4a*)&t[0]; nv1 = *(float4a*)&t[4];
        }
    }

    #pragma unroll
    for (int b = 0; b < 8; ++b) {
        const float4a v0 = nv0, v1 = nv1;
        if (b < 7) {
            const float* xrow = x + ((size_t)(bc0 + b + 1) * 256 + y) * 256;
            if (!edgeblk) {
                nv0 = *(const float4a*)(xrow + gxb);
                nv1 = *(const float4a*)(xrow + gxb + 4);
            } else {
                float t[8];
                #pragma unroll
                for (int i = 0; i < 8; ++i) {
                    int gx = gxb + i;
                    t[i] = ((unsigned)gx < 256u) ? xrow[gx] : 0.f;
                }
                nv0 = *(float4a*)&t[0]; nv1 = *(float4a*)&t[4];
            }
        }

        union { unsigned u[4]; bf16x8 v; } bb;
        bb.u[0] = pk2(v0.x, v0.y);
        bb.u[1] = pk2(v0.z, v0.w);
        bb.u[2] = pk2(v1.x, v1.y);
        bb.u[3] = pk2(v1.z, v1.w);
        const bf16x8 B = bb.v;

        const int bc = bc0 + b;
        #pragma unroll
        for (int mh = 0; mh < 2; ++mh) {
            f32x4 acc = zero;
            #pragma unroll
            for (int j = 0; j < 6; ++j) {
                f32x4 g = __builtin_amdgcn_mfma_f32_16x16x32_bf16(
                              A[j][mh], B, zero, 0, 0, 0);
                acc += g * c[j];               // x-interp blend, exact in f32
            }
            // C layout: col = px, row = 4q + reg  -> n_psf = mh*16 + 4q + reg
            float* p = out + (size_t)(bc * 32 + mh * 16 + q * 4) * 65536 + yoff;
            p[0]      = acc.x;                 // plain stores: let L2 merge
            p[65536]  = acc.y;                 // 64B half-lines into 128B lines
            p[131072] = acc.z;
            p[196608] = acc.w;
        }
    }
}

extern "C" void kernel_launch(void* const* d_in, const int* in_sizes, int n_in,
                              void* d_out, int out_size, void* d_ws, size_t ws_size,
                              hipStream_t stream) {
    const float* pw = (const float*)d_in[0];   // pre_weights [32,4096,31]
    const float* x  = (const float*)d_in[1];   // x [4,8,256,256] -> [32,256,256]
    float* out = (float*)d_out;                // [32,32,256,256] f32

    dim3 grid(4096, 1, 1);
    dim3 block(NTH, 1, 1);
    band_mfma<<<grid, block, 0, stream>>>(pw, x, out);
}